// Round 15
// baseline (352.692 us; speedup 1.0000x reference)
//
#include <hip/hip_runtime.h>
#include <math.h>

#define BATCH 32
#define CH 256
#define HW 4096
#define KSEL 8
#define EPSV 1e-5f

typedef __attribute__((ext_vector_type(8))) short short8;
typedef __attribute__((ext_vector_type(4))) float f32x4;

// ---- K1: raw-x Gram partials (256x256 per (b,q)) + fused s/sq partials ----
// PRODUCER/CONSUMER wave specialization (fix for the measured zero-overlap
// lockstep of R7..R14): 1024 threads = 16 waves; waves 0-7 = producers
// (coalesced loads + trunc-split convert + stats, R13's 512-thread staging
// map), waves 8-15 = consumers (ds_read + MFMA, acc[8][4] = 128x64 tile each).
// Hh/Hl double-buffered (128 KB LDS); ONE __syncthreads per chunk; producers
// fill buf[k+1] WHILE consumers drain buf[k] -- VMEM+VALU runs concurrently
// with LDS+MFMA on every SIMD (2 producer + 2 consumer waves each).
// Data path proven in R7: 4x256B coalesced wave loads; LDS stride 128B +
// 3-bit granule XOR (0 conflicts); C1 = H*(H+2L)^T trunc split (~1e-7 rel).
__global__ __launch_bounds__(1024) void gram256(const float* __restrict__ x,
                                                float* __restrict__ cosP,
                                                float* __restrict__ sP,
                                                float* __restrict__ sqP) {
    int z = blockIdx.x;             // 0..255
    int b = z >> 3, q = z & 7;      // klen = 512, 8 chunks of KC=64
    const float* xb = x + (size_t)b * CH * HW;

    __shared__ unsigned short Hh[2][CH * 64];   // 2 x 32 KB
    __shared__ unsigned short Hl[2][CH * 64];   // 2 x 32 KB

    int t = threadIdx.x, lane = t & 63, w = t >> 6;   // w 0..15

    // ---- producer geometry (threads 0..511 only) ----
    int rowbase = t >> 4;            // 0..31 ; row_i = rowbase + 32*i, i=0..7
    int col16 = t & 15;              // 16B chunk within the 256B row-chunk
    int gr = col16 >> 1;             // granule 0..7
    int halfo = (col16 & 1) * 4;     // short offset within granule
    const float4* srcb4 = (const float4*)xb + (size_t)rowbase * (HW / 4) + q * 128 + col16;

    // ---- consumer geometry (waves 8..15) ----
    int wcn = w - 8;                         // 0..7
    int arow = (wcn >> 2) * 128;             // row band (0 or 128)
    int wcol = (wcn & 3) * 64;               // col band
    int fr = lane & 15, fg = lane >> 4;

    float sl[8] = {}, sql[8] = {};
    f32x4 acc[8][4] = {};
    float4 f[8];

#define LOAD8(KB) { const float4* sp = srcb4 + (size_t)(KB) * 16;                  \
    _Pragma("unroll") for (int i = 0; i < 8; ++i) f[i] = sp[(size_t)i * 32768]; }

#define CONVERT8(BUF) { _Pragma("unroll") for (int i = 0; i < 8; ++i) {            \
    float4 v = f[i];                                                               \
    sl[i] += v.x + v.y + v.z + v.w;                                                \
    sql[i] += v.x * v.x + v.y * v.y + v.z * v.z + v.w * v.w;                       \
    unsigned u0 = __float_as_uint(v.x), u1 = __float_as_uint(v.y);                 \
    unsigned u2 = __float_as_uint(v.z), u3 = __float_as_uint(v.w);                 \
    unsigned hp0 = (u0 >> 16) | (u1 & 0xffff0000u);                                \
    unsigned hp1 = (u2 >> 16) | (u3 & 0xffff0000u);                                \
    float lo0 = v.x - __uint_as_float(u0 & 0xffff0000u);                           \
    float lo1 = v.y - __uint_as_float(u1 & 0xffff0000u);                           \
    float lo2 = v.z - __uint_as_float(u2 & 0xffff0000u);                           \
    float lo3 = v.w - __uint_as_float(u3 & 0xffff0000u);                           \
    lo0 += lo0; lo1 += lo1; lo2 += lo2; lo3 += lo3;                                \
    unsigned lp0 = (__float_as_uint(lo0) >> 16) | (__float_as_uint(lo1) & 0xffff0000u); \
    unsigned lp1 = (__float_as_uint(lo2) >> 16) | (__float_as_uint(lo3) & 0xffff0000u); \
    int r = rowbase + 32 * i;                                                      \
    int adr = r * 64 + ((gr ^ (r & 7)) * 8) + halfo;                               \
    *(uint2*)&Hh[BUF][adr] = make_uint2(hp0, hp1);                                 \
    *(uint2*)&Hl[BUF][adr] = make_uint2(lp0, lp1);                                 \
} }

#define MFMA_PHASE(BUF) { _Pragma("unroll") for (int ks = 0; ks < 2; ++ks) {       \
    int gk = ks * 4 + fg;                                                          \
    short8 af[8];                                                                  \
    _Pragma("unroll") for (int mi = 0; mi < 8; ++mi) {                             \
        int r = arow + mi * 16 + fr;                                               \
        af[mi] = *(const short8*)&Hh[BUF][r * 64 + ((gk ^ (r & 7)) * 8)];          \
    }                                                                              \
    _Pragma("unroll") for (int nj = 0; nj < 4; ++nj) {                             \
        int r = wcol + nj * 16 + fr;                                               \
        int rb = r * 64 + ((gk ^ (r & 7)) * 8);                                    \
        short8 bh = *(const short8*)&Hh[BUF][rb];                                  \
        short8 bl = *(const short8*)&Hl[BUF][rb];                                  \
        _Pragma("unroll") for (int mi = 0; mi < 8; ++mi) {                         \
            acc[mi][nj] = __builtin_amdgcn_mfma_f32_16x16x32_bf16(af[mi], bh, acc[mi][nj], 0, 0, 0); \
            acc[mi][nj] = __builtin_amdgcn_mfma_f32_16x16x32_bf16(af[mi], bl, acc[mi][nj], 0, 0, 0); \
        }                                                                          \
    }                                                                              \
} }

    // prologue: producers stage chunk 0 into buf 0
    if (w < 8) {
        LOAD8(0)
        CONVERT8(0)
    }
    __syncthreads();

#pragma unroll 1
    for (int kb = 0; kb < 8; ++kb) {
        if (w < 8) {
            if (kb < 7) {
                LOAD8(kb + 1)
                CONVERT8((kb + 1) & 1)      // fill the other buffer
            }
        } else {
            MFMA_PHASE(kb & 1)              // drain current buffer
        }
        __syncthreads();                    // swap point
    }

    // stats (producers): reduce across the 16 col-chunk threads of each row
    if (w < 8) {
#pragma unroll
        for (int i = 0; i < 8; ++i) {
#pragma unroll
            for (int off = 1; off < 16; off <<= 1) {
                sl[i] += __shfl_xor(sl[i], off);
                sql[i] += __shfl_xor(sql[i], off);
            }
        }
        if ((t & 15) == 0) {
#pragma unroll
            for (int i = 0; i < 8; ++i) {
                int r = rowbase + 32 * i;
                sP[(size_t)z * CH + r] = sl[i];
                sqP[(size_t)z * CH + r] = sql[i];
            }
        }
    } else {
        // C-write (consumers): 128x64 tile each
        float* Cp = cosP + (size_t)z * CH * CH;
#pragma unroll
        for (int mi = 0; mi < 8; ++mi)
#pragma unroll
            for (int nj = 0; nj < 4; ++nj) {
#pragma unroll
                for (int reg = 0; reg < 4; ++reg) {
                    int r = arow + mi * 16 + fg * 4 + reg;
                    int c = wcol + nj * 16 + fr;
                    Cp[(size_t)r * CH + c] = acc[mi][nj][reg];
                }
            }
    }
#undef LOAD8
#undef CONVERT8
#undef MFMA_PHASE
}

// ---- K2: finalize per-(b,c) stats from the 8 q-partials ----
__global__ __launch_bounds__(256) void finalize_kernel(const float* __restrict__ sP,
                                                       const float* __restrict__ sqP,
                                                       float* __restrict__ s,
                                                       float* __restrict__ sq,
                                                       float* __restrict__ invn) {
    int b = blockIdx.x, c = threadIdx.x;
    float S = 0.f, Q = 0.f;
#pragma unroll
    for (int q = 0; q < 8; ++q) {
        S += sP[(size_t)(b * 8 + q) * CH + c];
        Q += sqP[(size_t)(b * 8 + q) * CH + c];
    }
    s[b * CH + c] = S;
    sq[b * CH + c] = Q;
    invn[b * CH + c] = 1.0f / fmaxf(sqrtf(Q), 1e-12f);
}

// ---- K3: weighted sum of partials -> R[256][256] (invn applied per batch) ----
__global__ __launch_bounds__(1024) void reduceP(const float* __restrict__ cosP,
                                                const float* __restrict__ invn,
                                                float* __restrict__ R) {
    int r = blockIdx.x;
    int t = threadIdx.x;
    int d = t & 255, pg = t >> 8;          // 4 groups of 8 batches
    const float* base = cosP + (size_t)r * CH + d;
    float acc = 0.f;
    for (int b = pg * 8; b < pg * 8 + 8; ++b) {
        float part = 0.f;
#pragma unroll
        for (int q = 0; q < 8; ++q)
            part += base[(size_t)(b * 8 + q) * (CH * CH)];
        acc += part * invn[b * CH + d] * invn[b * CH + r];
    }
    __shared__ float red[1024];
    red[t] = acc;
    __syncthreads();
    if (t < 256)
        R[(size_t)r * CH + t] = red[t] + red[t + 256] + red[t + 512] + red[t + 768];
}

// -------- K4: symmetrize (R + R^T) + top-8 smallest |cos| per column --------
__global__ __launch_bounds__(256) void symtopk(const float* __restrict__ R,
                                               int* __restrict__ idx) {
    int c = blockIdx.x;
    int d = threadIdx.x;
    float v = fabsf((R[(size_t)c * CH + d] + R[(size_t)d * CH + c]) * (0.5f / BATCH));

    __shared__ unsigned long long keys[CH];
    __shared__ unsigned long long wmin[4];
    __shared__ unsigned long long bmin;

    keys[d] = ((unsigned long long)__float_as_uint(v) << 32) | (unsigned)d;
    __syncthreads();

    for (int i = 0; i < KSEL; ++i) {
        unsigned long long k = keys[d];
        for (int off = 32; off; off >>= 1) {
            unsigned long long o = __shfl_down(k, off);
            k = (o < k) ? o : k;
        }
        if ((d & 63) == 0) wmin[d >> 6] = k;
        __syncthreads();
        if (d == 0) {
            unsigned long long m = wmin[0];
            if (wmin[1] < m) m = wmin[1];
            if (wmin[2] < m) m = wmin[2];
            if (wmin[3] < m) m = wmin[3];
            bmin = m;
            idx[c * KSEL + i] = (int)(m & 0xffffffffu);
        }
        __syncthreads();
        int sel = (int)(bmin & 0xffffffffu);
        if (d == sel) keys[d] = 0xffffffffffffffffULL;
        __syncthreads();
    }
}

// ---------------- K5: gathered group statistics ----------------
__global__ __launch_bounds__(256) void groupstat_kernel(const float* __restrict__ s,
                                                        const float* __restrict__ sq,
                                                        const int* __restrict__ idx,
                                                        float* __restrict__ mean,
                                                        float* __restrict__ inv) {
    int b = blockIdx.x, c = threadIdx.x;
    float gs = s[b * CH + c], gq = sq[b * CH + c];
#pragma unroll
    for (int i = 1; i < KSEL; ++i) {
        int d = idx[c * KSEL + i];
        gs += s[b * CH + d];
        gq += sq[b * CH + d];
    }
    const float Ninv = 1.0f / (float)(KSEL * HW);
    float m = gs * Ninv;
    float var = gq * Ninv - m * m;
    mean[b * CH + c] = m;
    inv[b * CH + c]  = rsqrtf(var + EPSV);
}

// ---------------- K6: normalize ----------------
__global__ __launch_bounds__(256) void norm_kernel(const float* __restrict__ x,
                                                   const float* __restrict__ mean,
                                                   const float* __restrict__ inv,
                                                   const float* __restrict__ gamma,
                                                   const float* __restrict__ beta,
                                                   float* __restrict__ out) {
    int i = blockIdx.x * 256 + threadIdx.x;
    int bc = i >> 10;
    int c  = bc & (CH - 1);
    float m = mean[bc], v = inv[bc];
    float g  = gamma[c] * v;
    float bt = beta[c] - m * g;
    float4 xv = ((const float4*)x)[i];
    float4 o;
    o.x = xv.x * g + bt;
    o.y = xv.y * g + bt;
    o.z = xv.z * g + bt;
    o.w = xv.w * g + bt;
    ((float4*)out)[i] = o;
}

extern "C" void kernel_launch(void* const* d_in, const int* in_sizes, int n_in,
                              void* d_out, int out_size, void* d_ws, size_t ws_size,
                              hipStream_t stream) {
    const float* x     = (const float*)d_in[0];
    const float* gamma = (const float*)d_in[1];
    const float* beta  = (const float*)d_in[2];
    float* out = (float*)d_out;

    // Gram partials (256 x 256KB = 64 MB) live in d_out; norm overwrites at end.
    float* cosP = (float*)d_out;

    float* ws   = (float*)d_ws;
    float* sP   = ws;                         // 256*256 partial s
    float* sqP  = sP + 256 * CH;              // 256*256 partial sq
    float* s    = sqP + 256 * CH;
    float* sq   = s + BATCH * CH;
    float* invn = sq + BATCH * CH;
    float* mean = invn + BATCH * CH;
    float* inv  = mean + BATCH * CH;
    float* R    = inv + BATCH * CH;           // 256*256
    int*   idx  = (int*)(R + CH * CH);        // 256*8

    gram256<<<256, 1024, 0, stream>>>(x, cosP, sP, sqP);
    finalize_kernel<<<BATCH, 256, 0, stream>>>(sP, sqP, s, sq, invn);
    reduceP<<<CH, 1024, 0, stream>>>(cosP, invn, R);
    symtopk<<<CH, 256, 0, stream>>>(R, idx);
    groupstat_kernel<<<BATCH, 256, 0, stream>>>(s, sq, idx, mean, inv);
    norm_kernel<<<(BATCH * CH * HW / 4) / 256, 256, 0, stream>>>(x, mean, inv, gamma, beta, out);
}

// Round 16
// 103.945 us; speedup vs baseline: 3.3931x; 3.3931x over previous
//
#include <hip/hip_runtime.h>
#include <math.h>

#define BATCH 32
#define CH 256
#define HW 4096
#define KSEL 8
#define EPSV 1e-5f

typedef __attribute__((ext_vector_type(8))) short short8;
typedef __attribute__((ext_vector_type(4))) float f32x4;

// ---- K1: raw-x Gram partials (256x256 per (b,q)) + fused s/sq partials ----
// R13 structure (best measured: gram ~56us) + LDS DOUBLE-BUFFER with a SINGLE
// raw s_barrier per chunk. 1024 threads = 16 waves (4x4), wave tile 64x64,
// acc[4][4]=64 VGPR; total live ~120 <= the hard 128 cap of a 1024-thr block.
// Safety of one barrier: each wave's MFMA(k-1) ds_reads are data-dep complete
// before it reaches barrier(k); converts(k+1) (post-barrier(k)) write the
// OTHER buffer than MFMA(k) reads. Waves may slip a phase -> convert VALU of
// one wave overlaps MFMA of another on the same SIMD (m114).
// Data path = R7 proven: coalesced wave loads -> reg trunc-split convert ->
// LDS stride 128B + 3-bit granule XOR (0 conflicts) -> bf16 16x16x32 MFMA.
// C1 = H*(H+2L)^T trunc split (drops L*L^T, ~1e-7 rel).
__global__ __launch_bounds__(1024) void gram256(const float* __restrict__ x,
                                                float* __restrict__ cosP,
                                                float* __restrict__ sP,
                                                float* __restrict__ sqP) {
    int z = blockIdx.x;             // 0..255
    int b = z >> 3, q = z & 7;      // klen = 512
    const float* xb = x + (size_t)b * CH * HW;

    __shared__ unsigned short Hh[2][CH * 64];   // 2 x 32 KB
    __shared__ unsigned short Hl[2][CH * 64];   // 2 x 32 KB

    int t = threadIdx.x, lane = t & 63, w = t >> 6;   // w 0..15
    int wr = (w >> 2) * 64, wc = (w & 3) * 64;
    int fr = lane & 15, fg = lane >> 4;

    // staging geometry (coalesced: 4 x 1KB contiguous per wave-load instr)
    int rowbase = t >> 4;            // 0..63 ; row_i = rowbase + 64*i
    int col16 = t & 15;              // 16B chunk within the 256B row-chunk
    int gr = col16 >> 1;             // granule 0..7
    int halfo = (col16 & 1) * 4;     // short offset within granule
    const float4* srcb4 = (const float4*)xb + (size_t)rowbase * (HW / 4) + q * 128 + col16;

    float sl[4] = {}, sql[4] = {};
    f32x4 acc[4][4] = {};
    float4 f[4];

#define LOAD4(KB) { const float4* sp = srcb4 + (size_t)(KB) * 16;                  \
    _Pragma("unroll") for (int i = 0; i < 4; ++i) f[i] = sp[(size_t)i * 65536]; }

#define CONVERT4(BUF) { _Pragma("unroll") for (int i = 0; i < 4; ++i) {            \
    float4 v = f[i];                                                               \
    sl[i] += v.x + v.y + v.z + v.w;                                                \
    sql[i] += v.x * v.x + v.y * v.y + v.z * v.z + v.w * v.w;                       \
    unsigned u0 = __float_as_uint(v.x), u1 = __float_as_uint(v.y);                 \
    unsigned u2 = __float_as_uint(v.z), u3 = __float_as_uint(v.w);                 \
    unsigned hp0 = (u0 >> 16) | (u1 & 0xffff0000u);                                \
    unsigned hp1 = (u2 >> 16) | (u3 & 0xffff0000u);                                \
    float lo0 = v.x - __uint_as_float(u0 & 0xffff0000u);                           \
    float lo1 = v.y - __uint_as_float(u1 & 0xffff0000u);                           \
    float lo2 = v.z - __uint_as_float(u2 & 0xffff0000u);                           \
    float lo3 = v.w - __uint_as_float(u3 & 0xffff0000u);                           \
    lo0 += lo0; lo1 += lo1; lo2 += lo2; lo3 += lo3;                                \
    unsigned lp0 = (__float_as_uint(lo0) >> 16) | (__float_as_uint(lo1) & 0xffff0000u); \
    unsigned lp1 = (__float_as_uint(lo2) >> 16) | (__float_as_uint(lo3) & 0xffff0000u); \
    int r = rowbase + 64 * i;                                                      \
    int adr = r * 64 + ((gr ^ (r & 7)) * 8) + halfo;                               \
    *(uint2*)&Hh[BUF][adr] = make_uint2(hp0, hp1);                                 \
    *(uint2*)&Hl[BUF][adr] = make_uint2(lp0, lp1);                                 \
} }

#define MFMA_PHASE(BUF) { _Pragma("unroll") for (int ks = 0; ks < 2; ++ks) {       \
    int gk = ks * 4 + fg;                                                          \
    short8 af[4];                                                                  \
    _Pragma("unroll") for (int mi = 0; mi < 4; ++mi) {                             \
        int r = wr + mi * 16 + fr;                                                 \
        af[mi] = *(const short8*)&Hh[BUF][r * 64 + ((gk ^ (r & 7)) * 8)];          \
    }                                                                              \
    _Pragma("unroll") for (int nj = 0; nj < 4; ++nj) {                             \
        int r = wc + nj * 16 + fr;                                                 \
        int rb = r * 64 + ((gk ^ (r & 7)) * 8);                                    \
        short8 bh = *(const short8*)&Hh[BUF][rb];                                  \
        short8 bl = *(const short8*)&Hl[BUF][rb];                                  \
        _Pragma("unroll") for (int mi = 0; mi < 4; ++mi) {                         \
            acc[mi][nj] = __builtin_amdgcn_mfma_f32_16x16x32_bf16(af[mi], bh, acc[mi][nj], 0, 0, 0); \
            acc[mi][nj] = __builtin_amdgcn_mfma_f32_16x16x32_bf16(af[mi], bl, acc[mi][nj], 0, 0, 0); \
        }                                                                          \
    }                                                                              \
} }

    // prologue: issue chunk 0 loads
    LOAD4(0)

#pragma unroll 1
    for (int kb = 0; kb < 8; ++kb) {
        asm volatile("s_waitcnt vmcnt(0)" ::: "memory");   // f = chunk kb arrived
        __builtin_amdgcn_sched_barrier(0);
        CONVERT4(kb & 1)                                    // f -> buf[kb&1]
        if (kb < 7) LOAD4(kb + 1)                           // prefetch next chunk
        asm volatile("" ::: "memory");                      // pin load issue point
        asm volatile("s_waitcnt lgkmcnt(0)" ::: "memory");  // own ds_writes done
        __builtin_amdgcn_sched_barrier(0);
        __builtin_amdgcn_s_barrier();                       // buf[kb&1] ready (vmcnt NOT drained)
        __builtin_amdgcn_sched_barrier(0);
        __builtin_amdgcn_s_setprio(1);
        MFMA_PHASE(kb & 1)
        __builtin_amdgcn_s_setprio(0);
        // no trailing barrier: next convert targets the other buffer
    }

    // stats: reduce across the 16 col-chunk threads of each row
#pragma unroll
    for (int i = 0; i < 4; ++i) {
#pragma unroll
        for (int off = 1; off < 16; off <<= 1) {
            sl[i] += __shfl_xor(sl[i], off);
            sql[i] += __shfl_xor(sql[i], off);
        }
    }
    if ((t & 15) == 0) {
#pragma unroll
        for (int i = 0; i < 4; ++i) {
            int r = rowbase + 64 * i;
            sP[(size_t)z * CH + r] = sl[i];
            sqP[(size_t)z * CH + r] = sql[i];
        }
    }

    float* Cp = cosP + (size_t)z * CH * CH;
#pragma unroll
    for (int mi = 0; mi < 4; ++mi)
#pragma unroll
        for (int nj = 0; nj < 4; ++nj) {
#pragma unroll
            for (int reg = 0; reg < 4; ++reg) {
                int r = wr + mi * 16 + fg * 4 + reg;
                int c = wc + nj * 16 + fr;
                Cp[(size_t)r * CH + c] = acc[mi][nj][reg];
            }
        }
#undef LOAD4
#undef CONVERT4
#undef MFMA_PHASE
}

// ---- K2: finalize per-(b,c) stats from the 8 q-partials ----
__global__ __launch_bounds__(256) void finalize_kernel(const float* __restrict__ sP,
                                                       const float* __restrict__ sqP,
                                                       float* __restrict__ s,
                                                       float* __restrict__ sq,
                                                       float* __restrict__ invn) {
    int b = blockIdx.x, c = threadIdx.x;
    float S = 0.f, Q = 0.f;
#pragma unroll
    for (int q = 0; q < 8; ++q) {
        S += sP[(size_t)(b * 8 + q) * CH + c];
        Q += sqP[(size_t)(b * 8 + q) * CH + c];
    }
    s[b * CH + c] = S;
    sq[b * CH + c] = Q;
    invn[b * CH + c] = 1.0f / fmaxf(sqrtf(Q), 1e-12f);
}

// ---- K3: weighted sum of partials -> R[256][256] (invn applied per batch) ----
__global__ __launch_bounds__(1024) void reduceP(const float* __restrict__ cosP,
                                                const float* __restrict__ invn,
                                                float* __restrict__ R) {
    int r = blockIdx.x;
    int t = threadIdx.x;
    int d = t & 255, pg = t >> 8;          // 4 groups of 8 batches
    const float* base = cosP + (size_t)r * CH + d;
    float acc = 0.f;
    for (int b = pg * 8; b < pg * 8 + 8; ++b) {
        float part = 0.f;
#pragma unroll
        for (int q = 0; q < 8; ++q)
            part += base[(size_t)(b * 8 + q) * (CH * CH)];
        acc += part * invn[b * CH + d] * invn[b * CH + r];
    }
    __shared__ float red[1024];
    red[t] = acc;
    __syncthreads();
    if (t < 256)
        R[(size_t)r * CH + t] = red[t] + red[t + 256] + red[t + 512] + red[t + 768];
}

// -------- K4: symmetrize (R + R^T) + top-8 smallest |cos| per column --------
__global__ __launch_bounds__(256) void symtopk(const float* __restrict__ R,
                                               int* __restrict__ idx) {
    int c = blockIdx.x;
    int d = threadIdx.x;
    float v = fabsf((R[(size_t)c * CH + d] + R[(size_t)d * CH + c]) * (0.5f / BATCH));

    __shared__ unsigned long long keys[CH];
    __shared__ unsigned long long wmin[4];
    __shared__ unsigned long long bmin;

    keys[d] = ((unsigned long long)__float_as_uint(v) << 32) | (unsigned)d;
    __syncthreads();

    for (int i = 0; i < KSEL; ++i) {
        unsigned long long k = keys[d];
        for (int off = 32; off; off >>= 1) {
            unsigned long long o = __shfl_down(k, off);
            k = (o < k) ? o : k;
        }
        if ((d & 63) == 0) wmin[d >> 6] = k;
        __syncthreads();
        if (d == 0) {
            unsigned long long m = wmin[0];
            if (wmin[1] < m) m = wmin[1];
            if (wmin[2] < m) m = wmin[2];
            if (wmin[3] < m) m = wmin[3];
            bmin = m;
            idx[c * KSEL + i] = (int)(m & 0xffffffffu);
        }
        __syncthreads();
        int sel = (int)(bmin & 0xffffffffu);
        if (d == sel) keys[d] = 0xffffffffffffffffULL;
        __syncthreads();
    }
}

// ---------------- K5: gathered group statistics ----------------
__global__ __launch_bounds__(256) void groupstat_kernel(const float* __restrict__ s,
                                                        const float* __restrict__ sq,
                                                        const int* __restrict__ idx,
                                                        float* __restrict__ mean,
                                                        float* __restrict__ inv) {
    int b = blockIdx.x, c = threadIdx.x;
    float gs = s[b * CH + c], gq = sq[b * CH + c];
#pragma unroll
    for (int i = 1; i < KSEL; ++i) {
        int d = idx[c * KSEL + i];
        gs += s[b * CH + d];
        gq += sq[b * CH + d];
    }
    const float Ninv = 1.0f / (float)(KSEL * HW);
    float m = gs * Ninv;
    float var = gq * Ninv - m * m;
    mean[b * CH + c] = m;
    inv[b * CH + c]  = rsqrtf(var + EPSV);
}

// ---------------- K6: normalize ----------------
__global__ __launch_bounds__(256) void norm_kernel(const float* __restrict__ x,
                                                   const float* __restrict__ mean,
                                                   const float* __restrict__ inv,
                                                   const float* __restrict__ gamma,
                                                   const float* __restrict__ beta,
                                                   float* __restrict__ out) {
    int i = blockIdx.x * 256 + threadIdx.x;
    int bc = i >> 10;
    int c  = bc & (CH - 1);
    float m = mean[bc], v = inv[bc];
    float g  = gamma[c] * v;
    float bt = beta[c] - m * g;
    float4 xv = ((const float4*)x)[i];
    float4 o;
    o.x = xv.x * g + bt;
    o.y = xv.y * g + bt;
    o.z = xv.z * g + bt;
    o.w = xv.w * g + bt;
    ((float4*)out)[i] = o;
}

extern "C" void kernel_launch(void* const* d_in, const int* in_sizes, int n_in,
                              void* d_out, int out_size, void* d_ws, size_t ws_size,
                              hipStream_t stream) {
    const float* x     = (const float*)d_in[0];
    const float* gamma = (const float*)d_in[1];
    const float* beta  = (const float*)d_in[2];
    float* out = (float*)d_out;

    // Gram partials (256 x 256KB = 64 MB) live in d_out; norm overwrites at end.
    float* cosP = (float*)d_out;

    float* ws   = (float*)d_ws;
    float* sP   = ws;                         // 256*256 partial s
    float* sqP  = sP + 256 * CH;              // 256*256 partial sq
    float* s    = sqP + 256 * CH;
    float* sq   = s + BATCH * CH;
    float* invn = sq + BATCH * CH;
    float* mean = invn + BATCH * CH;
    float* inv  = mean + BATCH * CH;
    float* R    = inv + BATCH * CH;           // 256*256
    int*   idx  = (int*)(R + CH * CH);        // 256*8

    gram256<<<256, 1024, 0, stream>>>(x, cosP, sP, sqP);
    finalize_kernel<<<BATCH, 256, 0, stream>>>(sP, sqP, s, sq, invn);
    reduceP<<<CH, 1024, 0, stream>>>(cosP, invn, R);
    symtopk<<<CH, 256, 0, stream>>>(R, idx);
    groupstat_kernel<<<BATCH, 256, 0, stream>>>(s, sq, idx, mean, inv);
    norm_kernel<<<(BATCH * CH * HW / 4) / 256, 256, 0, stream>>>(x, mean, inv, gamma, beta, out);
}

// Round 17
// 103.214 us; speedup vs baseline: 3.4171x; 1.0071x over previous
//
#include <hip/hip_runtime.h>
#include <math.h>

#define BATCH 32
#define CH 256
#define HW 4096
#define KSEL 8
#define EPSV 1e-5f

typedef __attribute__((ext_vector_type(8))) short short8;
typedef __attribute__((ext_vector_type(4))) float f32x4;

// ---- K1: raw-x Gram partials (256x256 per (b,q)) + fused s/sq partials ----
// R16 structure (1024 thr = 16 waves 4x4, wave tile 64x64, acc[4][4]=64 VGPR,
// LDS dbuf 128KB, ONE raw s_barrier per chunk) with ALL scheduling pins
// removed except the required lgkmcnt(0) before the barrier (m141: pins cost
// -42%; m190: setprio negative on GEMM; compiler auto-emits counted vmcnt
// for the f-register data-dep). MFMA split into bh-pass then bl-pass so
// same-acc MFMAs have 16 independent instrs between them.
// Data path = R7 proven: coalesced wave loads -> reg trunc-split convert ->
// LDS stride 128B + 3-bit granule XOR (0 conflicts) -> bf16 16x16x32 MFMA.
// C1 = H*(H+2L)^T trunc split (drops L*L^T, ~1e-7 rel).
__global__ __launch_bounds__(1024) void gram256(const float* __restrict__ x,
                                                float* __restrict__ cosP,
                                                float* __restrict__ sP,
                                                float* __restrict__ sqP) {
    int z = blockIdx.x;             // 0..255
    int b = z >> 3, q = z & 7;      // klen = 512
    const float* xb = x + (size_t)b * CH * HW;

    __shared__ unsigned short Hh[2][CH * 64];   // 2 x 32 KB
    __shared__ unsigned short Hl[2][CH * 64];   // 2 x 32 KB

    int t = threadIdx.x, lane = t & 63, w = t >> 6;   // w 0..15
    int wr = (w >> 2) * 64, wc = (w & 3) * 64;
    int fr = lane & 15, fg = lane >> 4;

    // staging geometry (coalesced: 4 x 1KB contiguous per wave-load instr)
    int rowbase = t >> 4;            // 0..63 ; row_i = rowbase + 64*i
    int col16 = t & 15;              // 16B chunk within the 256B row-chunk
    int gr = col16 >> 1;             // granule 0..7
    int halfo = (col16 & 1) * 4;     // short offset within granule
    const float4* srcb4 = (const float4*)xb + (size_t)rowbase * (HW / 4) + q * 128 + col16;

    float sl[4] = {}, sql[4] = {};
    f32x4 acc[4][4] = {};
    float4 f[4];

#define LOAD4(KB) { const float4* sp = srcb4 + (size_t)(KB) * 16;                  \
    _Pragma("unroll") for (int i = 0; i < 4; ++i) f[i] = sp[(size_t)i * 65536]; }

#define CONVERT4(BUF) { _Pragma("unroll") for (int i = 0; i < 4; ++i) {            \
    float4 v = f[i];                                                               \
    sl[i] += v.x + v.y + v.z + v.w;                                                \
    sql[i] += v.x * v.x + v.y * v.y + v.z * v.z + v.w * v.w;                       \
    unsigned u0 = __float_as_uint(v.x), u1 = __float_as_uint(v.y);                 \
    unsigned u2 = __float_as_uint(v.z), u3 = __float_as_uint(v.w);                 \
    unsigned hp0 = (u0 >> 16) | (u1 & 0xffff0000u);                                \
    unsigned hp1 = (u2 >> 16) | (u3 & 0xffff0000u);                                \
    float lo0 = v.x - __uint_as_float(u0 & 0xffff0000u);                           \
    float lo1 = v.y - __uint_as_float(u1 & 0xffff0000u);                           \
    float lo2 = v.z - __uint_as_float(u2 & 0xffff0000u);                           \
    float lo3 = v.w - __uint_as_float(u3 & 0xffff0000u);                           \
    lo0 += lo0; lo1 += lo1; lo2 += lo2; lo3 += lo3;                                \
    unsigned lp0 = (__float_as_uint(lo0) >> 16) | (__float_as_uint(lo1) & 0xffff0000u); \
    unsigned lp1 = (__float_as_uint(lo2) >> 16) | (__float_as_uint(lo3) & 0xffff0000u); \
    int r = rowbase + 64 * i;                                                      \
    int adr = r * 64 + ((gr ^ (r & 7)) * 8) + halfo;                               \
    *(uint2*)&Hh[BUF][adr] = make_uint2(hp0, hp1);                                 \
    *(uint2*)&Hl[BUF][adr] = make_uint2(lp0, lp1);                                 \
} }

// bh-pass then bl-pass: same-acc MFMAs separated by 16 independent instrs.
#define MFMA_PHASE(BUF) { _Pragma("unroll") for (int ks = 0; ks < 2; ++ks) {       \
    int gk = ks * 4 + fg;                                                          \
    short8 af[4], bb[4];                                                           \
    _Pragma("unroll") for (int mi = 0; mi < 4; ++mi) {                             \
        int r = wr + mi * 16 + fr;                                                 \
        af[mi] = *(const short8*)&Hh[BUF][r * 64 + ((gk ^ (r & 7)) * 8)];          \
    }                                                                              \
    _Pragma("unroll") for (int nj = 0; nj < 4; ++nj) {                             \
        int r = wc + nj * 16 + fr;                                                 \
        bb[nj] = *(const short8*)&Hh[BUF][r * 64 + ((gk ^ (r & 7)) * 8)];          \
    }                                                                              \
    _Pragma("unroll") for (int nj = 0; nj < 4; ++nj)                               \
        _Pragma("unroll") for (int mi = 0; mi < 4; ++mi)                           \
            acc[mi][nj] = __builtin_amdgcn_mfma_f32_16x16x32_bf16(af[mi], bb[nj], acc[mi][nj], 0, 0, 0); \
    _Pragma("unroll") for (int nj = 0; nj < 4; ++nj) {                             \
        int r = wc + nj * 16 + fr;                                                 \
        bb[nj] = *(const short8*)&Hl[BUF][r * 64 + ((gk ^ (r & 7)) * 8)];          \
    }                                                                              \
    _Pragma("unroll") for (int nj = 0; nj < 4; ++nj)                               \
        _Pragma("unroll") for (int mi = 0; mi < 4; ++mi)                           \
            acc[mi][nj] = __builtin_amdgcn_mfma_f32_16x16x32_bf16(af[mi], bb[nj], acc[mi][nj], 0, 0, 0); \
} }

    // prologue: issue chunk 0 loads
    LOAD4(0)

#pragma unroll 1
    for (int kb = 0; kb < 8; ++kb) {
        CONVERT4(kb & 1)                                    // compiler inserts counted vmcnt per f-use
        if (kb < 7) LOAD4(kb + 1)                           // prefetch; compiler places optimally
        asm volatile("s_waitcnt lgkmcnt(0)" ::: "memory");  // own ds_writes done before barrier
        __builtin_amdgcn_sched_barrier(0);
        __builtin_amdgcn_s_barrier();                       // buf[kb&1] ready (vmcnt NOT drained)
        MFMA_PHASE(kb & 1)
        // no trailing barrier: next convert targets the other buffer
    }

    // stats: reduce across the 16 col-chunk threads of each row
#pragma unroll
    for (int i = 0; i < 4; ++i) {
#pragma unroll
        for (int off = 1; off < 16; off <<= 1) {
            sl[i] += __shfl_xor(sl[i], off);
            sql[i] += __shfl_xor(sql[i], off);
        }
    }
    if ((t & 15) == 0) {
#pragma unroll
        for (int i = 0; i < 4; ++i) {
            int r = rowbase + 64 * i;
            sP[(size_t)z * CH + r] = sl[i];
            sqP[(size_t)z * CH + r] = sql[i];
        }
    }

    float* Cp = cosP + (size_t)z * CH * CH;
#pragma unroll
    for (int mi = 0; mi < 4; ++mi)
#pragma unroll
        for (int nj = 0; nj < 4; ++nj) {
#pragma unroll
            for (int reg = 0; reg < 4; ++reg) {
                int r = wr + mi * 16 + fg * 4 + reg;
                int c = wc + nj * 16 + fr;
                Cp[(size_t)r * CH + c] = acc[mi][nj][reg];
            }
        }
#undef LOAD4
#undef CONVERT4
#undef MFMA_PHASE
}

// ---- K2: finalize per-(b,c) stats from the 8 q-partials ----
__global__ __launch_bounds__(256) void finalize_kernel(const float* __restrict__ sP,
                                                       const float* __restrict__ sqP,
                                                       float* __restrict__ s,
                                                       float* __restrict__ sq,
                                                       float* __restrict__ invn) {
    int b = blockIdx.x, c = threadIdx.x;
    float S = 0.f, Q = 0.f;
#pragma unroll
    for (int q = 0; q < 8; ++q) {
        S += sP[(size_t)(b * 8 + q) * CH + c];
        Q += sqP[(size_t)(b * 8 + q) * CH + c];
    }
    s[b * CH + c] = S;
    sq[b * CH + c] = Q;
    invn[b * CH + c] = 1.0f / fmaxf(sqrtf(Q), 1e-12f);
}

// ---- K3: weighted sum of partials -> R[256][256] (invn applied per batch) ----
__global__ __launch_bounds__(1024) void reduceP(const float* __restrict__ cosP,
                                                const float* __restrict__ invn,
                                                float* __restrict__ R) {
    int r = blockIdx.x;
    int t = threadIdx.x;
    int d = t & 255, pg = t >> 8;          // 4 groups of 8 batches
    const float* base = cosP + (size_t)r * CH + d;
    float acc = 0.f;
    for (int b = pg * 8; b < pg * 8 + 8; ++b) {
        float part = 0.f;
#pragma unroll
        for (int q = 0; q < 8; ++q)
            part += base[(size_t)(b * 8 + q) * (CH * CH)];
        acc += part * invn[b * CH + d] * invn[b * CH + r];
    }
    __shared__ float red[1024];
    red[t] = acc;
    __syncthreads();
    if (t < 256)
        R[(size_t)r * CH + t] = red[t] + red[t + 256] + red[t + 512] + red[t + 768];
}

// -------- K4: symmetrize (R + R^T) + top-8 smallest |cos| per column --------
__global__ __launch_bounds__(256) void symtopk(const float* __restrict__ R,
                                               int* __restrict__ idx) {
    int c = blockIdx.x;
    int d = threadIdx.x;
    float v = fabsf((R[(size_t)c * CH + d] + R[(size_t)d * CH + c]) * (0.5f / BATCH));

    __shared__ unsigned long long keys[CH];
    __shared__ unsigned long long wmin[4];
    __shared__ unsigned long long bmin;

    keys[d] = ((unsigned long long)__float_as_uint(v) << 32) | (unsigned)d;
    __syncthreads();

    for (int i = 0; i < KSEL; ++i) {
        unsigned long long k = keys[d];
        for (int off = 32; off; off >>= 1) {
            unsigned long long o = __shfl_down(k, off);
            k = (o < k) ? o : k;
        }
        if ((d & 63) == 0) wmin[d >> 6] = k;
        __syncthreads();
        if (d == 0) {
            unsigned long long m = wmin[0];
            if (wmin[1] < m) m = wmin[1];
            if (wmin[2] < m) m = wmin[2];
            if (wmin[3] < m) m = wmin[3];
            bmin = m;
            idx[c * KSEL + i] = (int)(m & 0xffffffffu);
        }
        __syncthreads();
        int sel = (int)(bmin & 0xffffffffu);
        if (d == sel) keys[d] = 0xffffffffffffffffULL;
        __syncthreads();
    }
}

// ---------------- K5: gathered group statistics ----------------
__global__ __launch_bounds__(256) void groupstat_kernel(const float* __restrict__ s,
                                                        const float* __restrict__ sq,
                                                        const int* __restrict__ idx,
                                                        float* __restrict__ mean,
                                                        float* __restrict__ inv) {
    int b = blockIdx.x, c = threadIdx.x;
    float gs = s[b * CH + c], gq = sq[b * CH + c];
#pragma unroll
    for (int i = 1; i < KSEL; ++i) {
        int d = idx[c * KSEL + i];
        gs += s[b * CH + d];
        gq += sq[b * CH + d];
    }
    const float Ninv = 1.0f / (float)(KSEL * HW);
    float m = gs * Ninv;
    float var = gq * Ninv - m * m;
    mean[b * CH + c] = m;
    inv[b * CH + c]  = rsqrtf(var + EPSV);
}

// ---------------- K6: normalize ----------------
__global__ __launch_bounds__(256) void norm_kernel(const float* __restrict__ x,
                                                   const float* __restrict__ mean,
                                                   const float* __restrict__ inv,
                                                   const float* __restrict__ gamma,
                                                   const float* __restrict__ beta,
                                                   float* __restrict__ out) {
    int i = blockIdx.x * 256 + threadIdx.x;
    int bc = i >> 10;
    int c  = bc & (CH - 1);
    float m = mean[bc], v = inv[bc];
    float g  = gamma[c] * v;
    float bt = beta[c] - m * g;
    float4 xv = ((const float4*)x)[i];
    float4 o;
    o.x = xv.x * g + bt;
    o.y = xv.y * g + bt;
    o.z = xv.z * g + bt;
    o.w = xv.w * g + bt;
    ((float4*)out)[i] = o;
}

extern "C" void kernel_launch(void* const* d_in, const int* in_sizes, int n_in,
                              void* d_out, int out_size, void* d_ws, size_t ws_size,
                              hipStream_t stream) {
    const float* x     = (const float*)d_in[0];
    const float* gamma = (const float*)d_in[1];
    const float* beta  = (const float*)d_in[2];
    float* out = (float*)d_out;

    // Gram partials (256 x 256KB = 64 MB) live in d_out; norm overwrites at end.
    float* cosP = (float*)d_out;

    float* ws   = (float*)d_ws;
    float* sP   = ws;                         // 256*256 partial s
    float* sqP  = sP + 256 * CH;              // 256*256 partial sq
    float* s    = sqP + 256 * CH;
    float* sq   = s + BATCH * CH;
    float* invn = sq + BATCH * CH;
    float* mean = invn + BATCH * CH;
    float* inv  = mean + BATCH * CH;
    float* R    = inv + BATCH * CH;           // 256*256
    int*   idx  = (int*)(R + CH * CH);        // 256*8

    gram256<<<256, 1024, 0, stream>>>(x, cosP, sP, sqP);
    finalize_kernel<<<BATCH, 256, 0, stream>>>(sP, sqP, s, sq, invn);
    reduceP<<<CH, 1024, 0, stream>>>(cosP, invn, R);
    symtopk<<<CH, 256, 0, stream>>>(R, idx);
    groupstat_kernel<<<BATCH, 256, 0, stream>>>(s, sq, idx, mean, inv);
    norm_kernel<<<(BATCH * CH * HW / 4) / 256, 256, 0, stream>>>(x, mean, inv, gamma, beta, out);
}